// Round 1
// baseline (715.104 us; speedup 1.0000x reference)
//
#include <hip/hip_runtime.h>
#include <cstdint>
#include <cstddef>

// ---------------------------------------------------------------------------
// ChunkedCrossAttention: h(4,2048,1024), e(4,32,2,128,1024)
// LN(h[:,63:]) -> Q; e -> K,V; per-(b,chunk,head) attn over 2*128 keys;
// O-proj + shifted residual.
// All GEMMs bf16 MFMA 16x16x32, f32 accumulate.
// ---------------------------------------------------------------------------

typedef float f32x4 __attribute__((ext_vector_type(4)));
typedef __bf16 bf16x8 __attribute__((ext_vector_type(8)));

static __device__ __forceinline__ ushort f2bf(float f) {
  union { float f; uint32_t u; } x; x.f = f;
  uint32_t r = x.u + 0x7fffu + ((x.u >> 16) & 1u);   // RTNE
  return (ushort)(r >> 16);
}

static __device__ __forceinline__ bf16x8 ld_frag(const ushort* p) {
  union { uint4 u; bf16x8 v; } x;
  x.u = *(const uint4*)p;
  return x.v;
}

// ---------------------------------------------------------------------------
// Weight transpose + cast: W (1024x1024 f32, KxN row-major) -> WT (NxK bf16)
// ---------------------------------------------------------------------------
__global__ __launch_bounds__(256) void transpose_cast(const float* __restrict__ W,
                                                      ushort* __restrict__ WT) {
  __shared__ float tile[64][65];
  const int t = threadIdx.x;
  const int n0 = blockIdx.x * 64, k0 = blockIdx.y * 64;
#pragma unroll
  for (int i = 0; i < 4; ++i) {
    int lid = i * 256 + t;
    int r = lid >> 4, c4 = (lid & 15) * 4;
    float4 v = *(const float4*)&W[(size_t)(k0 + r) * 1024 + n0 + c4];
    tile[r][c4 + 0] = v.x; tile[r][c4 + 1] = v.y;
    tile[r][c4 + 2] = v.z; tile[r][c4 + 3] = v.w;
  }
  __syncthreads();
#pragma unroll
  for (int i = 0; i < 4; ++i) {
    int lid = i * 256 + t;
    int n = lid >> 4, k4 = (lid & 15) * 4;
    ushort4 o;
    o.x = f2bf(tile[k4 + 0][n]); o.y = f2bf(tile[k4 + 1][n]);
    o.z = f2bf(tile[k4 + 2][n]); o.w = f2bf(tile[k4 + 3][n]);
    *(ushort4*)&WT[(size_t)(n0 + n) * 1024 + k0 + k4] = o;
  }
}

// ---------------------------------------------------------------------------
// LayerNorm: hh[b, s, :] = LN(h[b, 63+s, :]) for s<1985 else 0   (bf16 out)
// one block per (b,s); 256 threads x 4 cols
// ---------------------------------------------------------------------------
__global__ __launch_bounds__(256) void ln_kernel(const float* __restrict__ h,
                                                 const float* __restrict__ gamma,
                                                 const float* __restrict__ beta,
                                                 ushort* __restrict__ hh) {
  const int bx = blockIdx.x;
  const int b = bx >> 11, s = bx & 2047;
  const int t = threadIdx.x;
  ushort* orow = hh + (size_t)(b * 2048 + s) * 1024;
  if (s >= 1985) {
    ushort4 z; z.x = 0; z.y = 0; z.z = 0; z.w = 0;
    *(ushort4*)&orow[t * 4] = z;
    return;
  }
  const float* xrow = h + (size_t)(b * 2048 + 63 + s) * 1024;
  float4 x = *(const float4*)&xrow[t * 4];
  float s1 = x.x + x.y + x.z + x.w;
  float s2 = x.x * x.x + x.y * x.y + x.z * x.z + x.w * x.w;
#pragma unroll
  for (int off = 32; off > 0; off >>= 1) {
    s1 += __shfl_xor(s1, off);
    s2 += __shfl_xor(s2, off);
  }
  __shared__ float a1[4], a2[4];
  if ((t & 63) == 0) { a1[t >> 6] = s1; a2[t >> 6] = s2; }
  __syncthreads();
  s1 = a1[0] + a1[1] + a1[2] + a1[3];
  s2 = a2[0] + a2[1] + a2[2] + a2[3];
  const float mu = s1 * (1.0f / 1024.0f);
  const float var = s2 * (1.0f / 1024.0f) - mu * mu;
  const float rstd = rsqrtf(var + 1e-5f);
  float4 g = *(const float4*)&gamma[t * 4];
  float4 be = *(const float4*)&beta[t * 4];
  ushort4 o;
  o.x = f2bf((x.x - mu) * rstd * g.x + be.x);
  o.y = f2bf((x.y - mu) * rstd * g.y + be.y);
  o.z = f2bf((x.z - mu) * rstd * g.z + be.z);
  o.w = f2bf((x.w - mu) * rstd * g.w + be.w);
  *(ushort4*)&orow[t * 4] = o;
}

// ---------------------------------------------------------------------------
// GEMM: C[M,1024] = A[M,1024] @ Bt[1024,1024]^T + bias
//   A: f32 or bf16 (template), Bt: bf16 N x K row-major (pre-transposed W)
//   MODE 0: C -> bf16 buffer
//   MODE 1: final: f32 out with shifted residual: out[b, s+63, :] += ...
// 128x128 tile, BK=32, 256 threads (4 waves of 64x64), mfma 16x16x32 bf16.
// LDS rows padded to 40 elems (80 B): b128 frag reads are 2-way (free).
// ---------------------------------------------------------------------------
template <typename AT, int MODE>
__global__ __launch_bounds__(256) void gemm_kernel(const AT* __restrict__ A,
                                                   const ushort* __restrict__ Bt,
                                                   const float* __restrict__ bias,
                                                   ushort* __restrict__ Cbf,
                                                   float* __restrict__ Cf,
                                                   const float* __restrict__ resid) {
  __shared__ __align__(16) ushort Alds[128 * 40];
  __shared__ __align__(16) ushort Blds[128 * 40];
  const int t = threadIdx.x;
  const int m0 = blockIdx.y * 128, n0 = blockIdx.x * 128;
  const int lane = t & 63, wave = t >> 6;
  const int quad = lane >> 4, l16 = lane & 15;
  const int wrow = (wave >> 1) * 64, wcol = (wave & 1) * 64;

  f32x4 zero = {0.f, 0.f, 0.f, 0.f};
  f32x4 acc[4][4];
#pragma unroll
  for (int i = 0; i < 4; ++i)
#pragma unroll
    for (int j = 0; j < 4; ++j) acc[i][j] = zero;

  for (int kb = 0; kb < 32; ++kb) {
#pragma unroll
    for (int i = 0; i < 4; ++i) {
      int lid = i * 256 + t;
      int row = lid >> 3, c4 = (lid & 7) * 4;
      ushort4 o;
      if constexpr (sizeof(AT) == 4) {
        float4 v = *(const float4*)&A[(size_t)(m0 + row) * 1024 + kb * 32 + c4];
        o.x = f2bf(v.x); o.y = f2bf(v.y); o.z = f2bf(v.z); o.w = f2bf(v.w);
      } else {
        o = *(const ushort4*)&A[(size_t)(m0 + row) * 1024 + kb * 32 + c4];
      }
      *(ushort4*)&Alds[row * 40 + c4] = o;
      ushort4 o2 = *(const ushort4*)&Bt[(size_t)(n0 + row) * 1024 + kb * 32 + c4];
      *(ushort4*)&Blds[row * 40 + c4] = o2;
    }
    __syncthreads();
    bf16x8 af[4], bfv[4];
#pragma unroll
    for (int i = 0; i < 4; ++i)
      af[i] = ld_frag(&Alds[(wrow + i * 16 + l16) * 40 + quad * 8]);
#pragma unroll
    for (int j = 0; j < 4; ++j)
      bfv[j] = ld_frag(&Blds[(wcol + j * 16 + l16) * 40 + quad * 8]);
#pragma unroll
    for (int i = 0; i < 4; ++i)
#pragma unroll
      for (int j = 0; j < 4; ++j)
        acc[i][j] = __builtin_amdgcn_mfma_f32_16x16x32_bf16(af[i], bfv[j], acc[i][j], 0, 0, 0);
    __syncthreads();
  }

#pragma unroll
  for (int mi = 0; mi < 4; ++mi)
#pragma unroll
    for (int mj = 0; mj < 4; ++mj) {
      const int cc = n0 + wcol + mj * 16 + l16;
      const float bv = bias[cc];
#pragma unroll
      for (int rr = 0; rr < 4; ++rr) {
        const int r = m0 + wrow + mi * 16 + quad * 4 + rr;
        const float val = acc[mi][mj][rr] + bv;
        if constexpr (MODE == 0) {
          Cbf[(size_t)r * 1024 + cc] = f2bf(val);
        } else {
          const int b = r >> 11, s = r & 2047;
          if (s < 1985) {
            const size_t o = (size_t)(b * 2048 + s + 63) * 1024 + cc;
            Cf[o] = val + resid[o];
          }
        }
      }
    }
}

// ---------------------------------------------------------------------------
// Attention: one block per (b, chunk, head). 256 threads (4 waves).
// Q tile 64x64, K/V 256x64. S = QK^T * 0.125 (j split over waves),
// softmax over 256 via LDS partials, P -> LDS (bf16), O = P V via MFMA
// with V transposed in LDS. Output bf16 to Ob.
// ---------------------------------------------------------------------------
__global__ __launch_bounds__(256) void attn_kernel(const ushort* __restrict__ Qb,
                                                   const ushort* __restrict__ Kb,
                                                   const ushort* __restrict__ Vb,
                                                   ushort* __restrict__ Ob) {
  __shared__ __align__(16) ushort Qs[64 * 72];    //  9216 B
  __shared__ __align__(16) ushort Ks[256 * 72];   // 36864 B
  __shared__ __align__(16) ushort Vt[64 * 280];   // 35840 B (transposed: [d][j])
  __shared__ __align__(16) ushort Ps[64 * 280];   // 35840 B
  __shared__ float redm[4][64];
  __shared__ float reds[4][64];

  const int t = threadIdx.x;
  const int bx = blockIdx.x;
  const int hd = bx & 15, c = (bx >> 4) & 31, b = bx >> 9;
  const int lane = t & 63, wave = t >> 6;
  const int quad = lane >> 4, l16 = lane & 15;

  const int qrow0 = b * 2048 + c * 64;
  const int kvrow0 = (b * 32 + c) * 256;
  const int colh = hd * 64;

  // load Q (64 x 64)
#pragma unroll
  for (int it = 0; it < 2; ++it) {
    int lid = it * 256 + t;
    int r = lid >> 3, ch = (lid & 7) * 8;
    uint4 v = *(const uint4*)&Qb[(size_t)(qrow0 + r) * 1024 + colh + ch];
    *(uint4*)&Qs[r * 72 + ch] = v;
  }
  // load K (256 x 64)
#pragma unroll
  for (int it = 0; it < 8; ++it) {
    int lid = it * 256 + t;
    int r = lid >> 3, ch = (lid & 7) * 8;
    uint4 v = *(const uint4*)&Kb[(size_t)(kvrow0 + r) * 1024 + colh + ch];
    *(uint4*)&Ks[r * 72 + ch] = v;
  }
  // load V transposed: Vt[d][j]
#pragma unroll
  for (int it = 0; it < 8; ++it) {
    int lid = it * 256 + t;
    int r = lid >> 3, ch = (lid & 7) * 8;
    uint4 v = *(const uint4*)&Vb[(size_t)(kvrow0 + r) * 1024 + colh + ch];
    uint32_t u0 = v.x, u1 = v.y, u2 = v.z, u3 = v.w;
    Vt[(ch + 0) * 280 + r] = (ushort)(u0 & 0xffff);
    Vt[(ch + 1) * 280 + r] = (ushort)(u0 >> 16);
    Vt[(ch + 2) * 280 + r] = (ushort)(u1 & 0xffff);
    Vt[(ch + 3) * 280 + r] = (ushort)(u1 >> 16);
    Vt[(ch + 4) * 280 + r] = (ushort)(u2 & 0xffff);
    Vt[(ch + 5) * 280 + r] = (ushort)(u2 >> 16);
    Vt[(ch + 6) * 280 + r] = (ushort)(u3 & 0xffff);
    Vt[(ch + 7) * 280 + r] = (ushort)(u3 >> 16);
  }
  __syncthreads();

  // ---- S = Q K^T for this wave's 64 j columns ----
  const int jw = wave * 64;
  f32x4 zero = {0.f, 0.f, 0.f, 0.f};
  f32x4 acc[4][4];
#pragma unroll
  for (int i = 0; i < 4; ++i)
#pragma unroll
    for (int j = 0; j < 4; ++j) acc[i][j] = zero;

#pragma unroll
  for (int kb = 0; kb < 2; ++kb) {
    bf16x8 af[4], bfv[4];
#pragma unroll
    for (int mi = 0; mi < 4; ++mi)
      af[mi] = ld_frag(&Qs[(mi * 16 + l16) * 72 + kb * 32 + quad * 8]);
#pragma unroll
    for (int mj = 0; mj < 4; ++mj)
      bfv[mj] = ld_frag(&Ks[(jw + mj * 16 + l16) * 72 + kb * 32 + quad * 8]);
#pragma unroll
    for (int mi = 0; mi < 4; ++mi)
#pragma unroll
      for (int mj = 0; mj < 4; ++mj)
        acc[mi][mj] = __builtin_amdgcn_mfma_f32_16x16x32_bf16(af[mi], bfv[mj], acc[mi][mj], 0, 0, 0);
  }
#pragma unroll
  for (int mi = 0; mi < 4; ++mi)
#pragma unroll
    for (int mj = 0; mj < 4; ++mj) acc[mi][mj] = acc[mi][mj] * 0.125f;

  // ---- softmax over 256 (cross-wave via LDS partials) ----
  float rmax[4][4];
#pragma unroll
  for (int mi = 0; mi < 4; ++mi)
#pragma unroll
    for (int rr = 0; rr < 4; ++rr) {
      float m = fmaxf(fmaxf(acc[mi][0][rr], acc[mi][1][rr]),
                      fmaxf(acc[mi][2][rr], acc[mi][3][rr]));
      m = fmaxf(m, __shfl_xor(m, 1));
      m = fmaxf(m, __shfl_xor(m, 2));
      m = fmaxf(m, __shfl_xor(m, 4));
      m = fmaxf(m, __shfl_xor(m, 8));
      rmax[mi][rr] = m;
    }
  if (l16 == 0) {
#pragma unroll
    for (int mi = 0; mi < 4; ++mi)
#pragma unroll
      for (int rr = 0; rr < 4; ++rr)
        redm[wave][mi * 16 + quad * 4 + rr] = rmax[mi][rr];
  }
  __syncthreads();
  float gmax[4][4];
#pragma unroll
  for (int mi = 0; mi < 4; ++mi)
#pragma unroll
    for (int rr = 0; rr < 4; ++rr) {
      const int row = mi * 16 + quad * 4 + rr;
      gmax[mi][rr] = fmaxf(fmaxf(redm[0][row], redm[1][row]),
                           fmaxf(redm[2][row], redm[3][row]));
    }
  float rsum[4][4];
#pragma unroll
  for (int mi = 0; mi < 4; ++mi)
#pragma unroll
    for (int rr = 0; rr < 4; ++rr) {
      float s = 0.f;
#pragma unroll
      for (int mj = 0; mj < 4; ++mj) {
        float p = exp2f((acc[mi][mj][rr] - gmax[mi][rr]) * 1.4426950408889634f);
        acc[mi][mj][rr] = p;
        s += p;
      }
      s += __shfl_xor(s, 1);
      s += __shfl_xor(s, 2);
      s += __shfl_xor(s, 4);
      s += __shfl_xor(s, 8);
      rsum[mi][rr] = s;
    }
  if (l16 == 0) {
#pragma unroll
    for (int mi = 0; mi < 4; ++mi)
#pragma unroll
      for (int rr = 0; rr < 4; ++rr)
        reds[wave][mi * 16 + quad * 4 + rr] = rsum[mi][rr];
  }
  __syncthreads();
  // write normalized P (bf16) to LDS
#pragma unroll
  for (int mi = 0; mi < 4; ++mi)
#pragma unroll
    for (int rr = 0; rr < 4; ++rr) {
      const int row = mi * 16 + quad * 4 + rr;
      const float inv = 1.0f / (reds[0][row] + reds[1][row] + reds[2][row] + reds[3][row]);
#pragma unroll
      for (int mj = 0; mj < 4; ++mj)
        Ps[row * 280 + jw + mj * 16 + l16] = f2bf(acc[mi][mj][rr] * inv);
    }
  __syncthreads();

  // ---- O = P V : this wave handles d-slice [wave*16, wave*16+16) ----
  const int d0 = wave * 16;
  f32x4 acc2[4];
#pragma unroll
  for (int mi = 0; mi < 4; ++mi) acc2[mi] = zero;
#pragma unroll
  for (int kb = 0; kb < 8; ++kb) {
    bf16x8 bfv = ld_frag(&Vt[(d0 + l16) * 280 + kb * 32 + quad * 8]);
#pragma unroll
    for (int mi = 0; mi < 4; ++mi) {
      bf16x8 af = ld_frag(&Ps[(mi * 16 + l16) * 280 + kb * 32 + quad * 8]);
      acc2[mi] = __builtin_amdgcn_mfma_f32_16x16x32_bf16(af, bfv, acc2[mi], 0, 0, 0);
    }
  }
#pragma unroll
  for (int mi = 0; mi < 4; ++mi)
#pragma unroll
    for (int rr = 0; rr < 4; ++rr) {
      const int i = mi * 16 + quad * 4 + rr;
      Ob[(size_t)(qrow0 + i) * 1024 + colh + d0 + l16] = f2bf(acc2[mi][rr]);
    }
}

// ---------------------------------------------------------------------------
// head rows 0..62 of each batch: pure residual copy
// ---------------------------------------------------------------------------
__global__ __launch_bounds__(256) void head_copy(const float* __restrict__ h,
                                                 float* __restrict__ out) {
  const int idx4 = blockIdx.x * 256 + threadIdx.x;   // 0 .. 64511
  const int b = idx4 / 16128;
  const int rem = idx4 - b * 16128;
  const size_t o = (size_t)b * 2048 * 1024 + (size_t)rem * 4;
  *(float4*)&out[o] = *(const float4*)&h[o];
}

// ---------------------------------------------------------------------------
extern "C" void kernel_launch(void* const* d_in, const int* in_sizes, int n_in,
                              void* d_out, int out_size, void* d_ws, size_t ws_size,
                              hipStream_t stream) {
  const float* h     = (const float*)d_in[0];
  const float* e     = (const float*)d_in[1];
  const float* Wq    = (const float*)d_in[2];
  const float* bq    = (const float*)d_in[3];
  const float* Wk    = (const float*)d_in[4];
  const float* bk    = (const float*)d_in[5];
  const float* Wv    = (const float*)d_in[6];
  const float* bv    = (const float*)d_in[7];
  const float* Wo    = (const float*)d_in[8];
  const float* bo    = (const float*)d_in[9];
  const float* gamma = (const float*)d_in[10];
  const float* beta  = (const float*)d_in[11];
  float* out = (float*)d_out;

  char* ws = (char*)d_ws;
  ushort* WqT = (ushort*)(ws + ((size_t)0 << 20));    // 2 MiB
  ushort* WkT = (ushort*)(ws + ((size_t)2 << 20));    // 2 MiB
  ushort* WvT = (ushort*)(ws + ((size_t)4 << 20));    // 2 MiB
  ushort* WoT = (ushort*)(ws + ((size_t)6 << 20));    // 2 MiB
  ushort* hhb = (ushort*)(ws + ((size_t)8 << 20));    // 16 MiB (8192x1024 bf16)
  ushort* Qb  = (ushort*)(ws + ((size_t)24 << 20));   // 16 MiB
  ushort* Kb  = (ushort*)(ws + ((size_t)40 << 20));   // 64 MiB (32768x1024 bf16)
  ushort* Vb  = (ushort*)(ws + ((size_t)104 << 20));  // 64 MiB
  ushort* Ob  = (ushort*)(ws + ((size_t)168 << 20));  // 16 MiB

  // 1. weights -> bf16 transposed
  transpose_cast<<<dim3(16, 16), 256, 0, stream>>>(Wq, WqT);
  transpose_cast<<<dim3(16, 16), 256, 0, stream>>>(Wk, WkT);
  transpose_cast<<<dim3(16, 16), 256, 0, stream>>>(Wv, WvT);
  transpose_cast<<<dim3(16, 16), 256, 0, stream>>>(Wo, WoT);

  // 2. LayerNorm -> hh (bf16, padded)
  ln_kernel<<<8192, 256, 0, stream>>>(h, gamma, beta, hhb);

  // 3. projections
  gemm_kernel<ushort, 0><<<dim3(8, 64), 256, 0, stream>>>(hhb, WqT, bq, Qb, nullptr, nullptr);
  gemm_kernel<float, 0><<<dim3(8, 256), 256, 0, stream>>>(e, WkT, bk, Kb, nullptr, nullptr);
  gemm_kernel<float, 0><<<dim3(8, 256), 256, 0, stream>>>(e, WvT, bv, Vb, nullptr, nullptr);

  // 4. attention per (b, chunk, head)
  attn_kernel<<<2048, 256, 0, stream>>>(Qb, Kb, Vb, Ob);

  // 5. output projection + shifted residual (f32 out), plus first-63-row copy
  gemm_kernel<ushort, 1><<<dim3(8, 64), 256, 0, stream>>>(Ob, WoT, bo, nullptr, out, h);
  head_copy<<<252, 256, 0, stream>>>(h, out);
}

// Round 3
// 609.549 us; speedup vs baseline: 1.1732x; 1.1732x over previous
//
#include <hip/hip_runtime.h>
#include <cstdint>
#include <cstddef>

// ---------------------------------------------------------------------------
// ChunkedCrossAttention: h(4,2048,1024), e(4,32,2,128,1024)
// LN(h[:,63:]) -> Q; e -> K,V; per-(b,chunk,head) attn over 2*128 keys;
// O-proj + shifted residual. GEMMs: bf16 MFMA 16x16x32, f32 accumulate,
// m97-style global_load_lds staging + XCD-aware swizzle.
// Workspace capped at 184 MiB (proven safe in round 1): e is cast to bf16 in
// 16 MiB quarters through the dead hhb buffer.
// ---------------------------------------------------------------------------

typedef float f32x4 __attribute__((ext_vector_type(4)));
typedef __bf16 bf16x8 __attribute__((ext_vector_type(8)));

static __device__ __forceinline__ ushort f2bf(float f) {
  union { float f; uint32_t u; } x; x.f = f;
  uint32_t r = x.u + 0x7fffu + ((x.u >> 16) & 1u);   // RTNE
  return (ushort)(r >> 16);
}

static __device__ __forceinline__ bf16x8 ld_frag(const ushort* p) {
  union { uint4 u; bf16x8 v; } x;
  x.u = *(const uint4*)p;
  return x.v;
}

// async global->LDS, 16 B per lane. HW semantics: LDS dest is wave-uniform
// base + lane*16 (we pass the per-lane pointer; compiler uniformizes to the
// lane-0 base, which matches our lane*16 layout). Proper addrspace casts —
// NO 32-bit truncation of a flat pointer.
static __device__ __forceinline__ void gl2lds16(const ushort* g, ushort* l) {
  __builtin_amdgcn_global_load_lds(
      (const __attribute__((address_space(1))) void*)g,
      (__attribute__((address_space(3))) void*)l,
      16, 0, 0);
}

// ---------------------------------------------------------------------------
// Weight transpose + cast: W (1024x1024 f32, KxN row-major) -> WT (NxK bf16)
// ---------------------------------------------------------------------------
__global__ __launch_bounds__(256) void transpose_cast(const float* __restrict__ W,
                                                      ushort* __restrict__ WT) {
  __shared__ float tile[64][65];
  const int t = threadIdx.x;
  const int n0 = blockIdx.x * 64, k0 = blockIdx.y * 64;
#pragma unroll
  for (int i = 0; i < 4; ++i) {
    int lid = i * 256 + t;
    int r = lid >> 4, c4 = (lid & 15) * 4;
    float4 v = *(const float4*)&W[(size_t)(k0 + r) * 1024 + n0 + c4];
    tile[r][c4 + 0] = v.x; tile[r][c4 + 1] = v.y;
    tile[r][c4 + 2] = v.z; tile[r][c4 + 3] = v.w;
  }
  __syncthreads();
#pragma unroll
  for (int i = 0; i < 4; ++i) {
    int lid = i * 256 + t;
    int n = lid >> 4, k4 = (lid & 15) * 4;
    ushort4 o;
    o.x = f2bf(tile[k4 + 0][n]); o.y = f2bf(tile[k4 + 1][n]);
    o.z = f2bf(tile[k4 + 2][n]); o.w = f2bf(tile[k4 + 3][n]);
    *(ushort4*)&WT[(size_t)(n0 + n) * 1024 + k0 + k4] = o;
  }
}

// ---------------------------------------------------------------------------
// cast f32 -> bf16, 8 elems/thread
// ---------------------------------------------------------------------------
__global__ __launch_bounds__(256) void cast_bf16(const float* __restrict__ x,
                                                 ushort* __restrict__ y) {
  const size_t i = ((size_t)blockIdx.x * 256 + threadIdx.x) * 8;
  float4 a = *(const float4*)&x[i];
  float4 b = *(const float4*)&x[i + 4];
  ushort o[8];
  o[0] = f2bf(a.x); o[1] = f2bf(a.y); o[2] = f2bf(a.z); o[3] = f2bf(a.w);
  o[4] = f2bf(b.x); o[5] = f2bf(b.y); o[6] = f2bf(b.z); o[7] = f2bf(b.w);
  *(uint4*)&y[i] = *(const uint4*)o;
}

// ---------------------------------------------------------------------------
// LayerNorm: hh[b, s, :] = LN(h[b, 63+s, :]) for s<1985 else 0   (bf16 out)
// ---------------------------------------------------------------------------
__global__ __launch_bounds__(256) void ln_kernel(const float* __restrict__ h,
                                                 const float* __restrict__ gamma,
                                                 const float* __restrict__ beta,
                                                 ushort* __restrict__ hh) {
  const int bx = blockIdx.x;
  const int b = bx >> 11, s = bx & 2047;
  const int t = threadIdx.x;
  ushort* orow = hh + (size_t)(b * 2048 + s) * 1024;
  if (s >= 1985) {
    ushort4 z; z.x = 0; z.y = 0; z.z = 0; z.w = 0;
    *(ushort4*)&orow[t * 4] = z;
    return;
  }
  const float* xrow = h + (size_t)(b * 2048 + 63 + s) * 1024;
  float4 x = *(const float4*)&xrow[t * 4];
  float s1 = x.x + x.y + x.z + x.w;
  float s2 = x.x * x.x + x.y * x.y + x.z * x.z + x.w * x.w;
#pragma unroll
  for (int off = 32; off > 0; off >>= 1) {
    s1 += __shfl_xor(s1, off);
    s2 += __shfl_xor(s2, off);
  }
  __shared__ float a1[4], a2[4];
  if ((t & 63) == 0) { a1[t >> 6] = s1; a2[t >> 6] = s2; }
  __syncthreads();
  s1 = a1[0] + a1[1] + a1[2] + a1[3];
  s2 = a2[0] + a2[1] + a2[2] + a2[3];
  const float mu = s1 * (1.0f / 1024.0f);
  const float var = s2 * (1.0f / 1024.0f) - mu * mu;
  const float rstd = rsqrtf(var + 1e-5f);
  float4 g = *(const float4*)&gamma[t * 4];
  float4 be = *(const float4*)&beta[t * 4];
  ushort4 o;
  o.x = f2bf((x.x - mu) * rstd * g.x + be.x);
  o.y = f2bf((x.y - mu) * rstd * g.y + be.y);
  o.z = f2bf((x.z - mu) * rstd * g.z + be.z);
  o.w = f2bf((x.w - mu) * rstd * g.w + be.w);
  *(ushort4*)&orow[t * 4] = o;
}

// ---------------------------------------------------------------------------
// GEMM (m97-style): C[M,1024] = A[M,1024](bf16) @ Bt[1024,1024]^T(bf16) + bias
//   MODE 0: C -> bf16;  MODE 1: f32 out, shifted residual add.
// 128x128 tile, BK=32, 256 threads (4 waves), global_load_lds x16 staging,
// unpadded 128x32 LDS tiles, XCD-aware block swizzle (ntiles = 8).
// ---------------------------------------------------------------------------
template <int MODE>
__global__ __launch_bounds__(256) void gemm_bf16(const ushort* __restrict__ A,
                                                 const ushort* __restrict__ Bt,
                                                 const float* __restrict__ bias,
                                                 ushort* __restrict__ Cbf,
                                                 float* __restrict__ Cf,
                                                 const float* __restrict__ resid,
                                                 int mtiles, int mrow_off) {
  __shared__ __align__(16) ushort Alds[128 * 32];
  __shared__ __align__(16) ushort Blds[128 * 32];
  const int t = threadIdx.x;
  const int lane = t & 63, wave = t >> 6;
  const int quad = lane >> 4, l16 = lane & 15;

  // XCD swizzle: each XCD (L%8) owns a contiguous M-range x all 8 N-tiles.
  const int L = blockIdx.x;
  const int xcd = L & 7, slot = L >> 3;
  const int mt = xcd * (mtiles >> 3) + (slot >> 3);
  const int nt = slot & 7;
  const int m0 = mt * 128, n0 = nt * 128;

  // staging: 8 chunks of 16 rows x 32 cols per tile; wave w does chunks 2w,2w+1
  const int srow = lane >> 2;          // 0..15
  const int scol = (lane & 3) * 8;     // 0,8,16,24
  const int c0 = wave * 2;
  const ushort* gA0 = A  + (size_t)(m0 + c0 * 16 + srow) * 1024 + scol;
  const ushort* gA1 = gA0 + 16 * 1024;
  const ushort* gB0 = Bt + (size_t)(n0 + c0 * 16 + srow) * 1024 + scol;
  const ushort* gB1 = gB0 + 16 * 1024;
  ushort* dA0 = &Alds[c0 * 512 + lane * 8];
  ushort* dA1 = dA0 + 512;
  ushort* dB0 = &Blds[c0 * 512 + lane * 8];
  ushort* dB1 = dB0 + 512;

  const int wrow = (wave >> 1) * 64, wcol = (wave & 1) * 64;
  const ushort* pA = &Alds[(wrow + l16) * 32 + quad * 8];
  const ushort* pB = &Blds[(wcol + l16) * 32 + quad * 8];

  f32x4 zero = {0.f, 0.f, 0.f, 0.f};
  f32x4 acc[4][4];
#pragma unroll
  for (int i = 0; i < 4; ++i)
#pragma unroll
    for (int j = 0; j < 4; ++j) acc[i][j] = zero;

  for (int kb = 0; kb < 32; ++kb) {
    const int ko = kb * 32;
    gl2lds16(gA0 + ko, dA0);
    gl2lds16(gA1 + ko, dA1);
    gl2lds16(gB0 + ko, dB0);
    gl2lds16(gB1 + ko, dB1);
    __syncthreads();
    bf16x8 af[4], bfv[4];
#pragma unroll
    for (int i = 0; i < 4; ++i) af[i]  = ld_frag(pA + i * 16 * 32);
#pragma unroll
    for (int j = 0; j < 4; ++j) bfv[j] = ld_frag(pB + j * 16 * 32);
#pragma unroll
    for (int i = 0; i < 4; ++i)
#pragma unroll
      for (int j = 0; j < 4; ++j)
        acc[i][j] = __builtin_amdgcn_mfma_f32_16x16x32_bf16(af[i], bfv[j], acc[i][j], 0, 0, 0);
    __syncthreads();
  }

#pragma unroll
  for (int mi = 0; mi < 4; ++mi)
#pragma unroll
    for (int mj = 0; mj < 4; ++mj) {
      const int cc = n0 + wcol + mj * 16 + l16;
      const float bv = bias[cc];
#pragma unroll
      for (int rr = 0; rr < 4; ++rr) {
        const int r = m0 + wrow + mi * 16 + quad * 4 + rr;
        const float val = acc[mi][mj][rr] + bv;
        if constexpr (MODE == 0) {
          Cbf[(size_t)r * 1024 + cc] = f2bf(val);
        } else {
          const int gr = r + mrow_off;
          const int b = gr >> 11, s = gr & 2047;
          if (s < 1985) {
            const size_t o = (size_t)(b * 2048 + s + 63) * 1024 + cc;
            Cf[o] = val + resid[o];
          }
        }
      }
    }
}

// ---------------------------------------------------------------------------
// Attention: one block per (b, chunk, head). 256 threads (4 waves).
// LDS overlay (Ps reuses Qs+Ks region after S-phase) -> 80 KiB, 2 blocks/CU.
// ---------------------------------------------------------------------------
__global__ __launch_bounds__(256) void attn_kernel(const ushort* __restrict__ Qb,
                                                   const ushort* __restrict__ Kb,
                                                   const ushort* __restrict__ Vb,
                                                   ushort* __restrict__ Ob) {
  // Qs: 64x72 (4608) | Ks: 256x72 (18432) | Vt: 64x264 (16896)  [elems]
  // Ps: 64x264 (16896) overlays Qs+Ks (23040)
  __shared__ __align__(16) ushort smem[4608 + 18432 + 16896];   // 79872 B
  __shared__ float redm[4][64];
  __shared__ float reds[4][64];
  ushort* Qs = smem;
  ushort* Ks = smem + 4608;
  ushort* Vt = smem + 23040;
  ushort* Ps = smem;

  const int t = threadIdx.x;
  const int bx = blockIdx.x;
  const int hd = bx & 15, c = (bx >> 4) & 31, b = bx >> 9;
  const int lane = t & 63, wave = t >> 6;
  const int quad = lane >> 4, l16 = lane & 15;

  const int qrow0 = b * 2048 + c * 64;
  const int kvrow0 = (b * 32 + c) * 256;
  const int colh = hd * 64;

  // load Q (64 x 64)
#pragma unroll
  for (int it = 0; it < 2; ++it) {
    int lid = it * 256 + t;
    int r = lid >> 3, ch = (lid & 7) * 8;
    uint4 v = *(const uint4*)&Qb[(size_t)(qrow0 + r) * 1024 + colh + ch];
    *(uint4*)&Qs[r * 72 + ch] = v;
  }
  // load K (256 x 64)
#pragma unroll
  for (int it = 0; it < 8; ++it) {
    int lid = it * 256 + t;
    int r = lid >> 3, ch = (lid & 7) * 8;
    uint4 v = *(const uint4*)&Kb[(size_t)(kvrow0 + r) * 1024 + colh + ch];
    *(uint4*)&Ks[r * 72 + ch] = v;
  }
  // load V transposed: Vt[d][j], stride 264
#pragma unroll
  for (int it = 0; it < 8; ++it) {
    int lid = it * 256 + t;
    int r = lid >> 3, ch = (lid & 7) * 8;
    uint4 v = *(const uint4*)&Vb[(size_t)(kvrow0 + r) * 1024 + colh + ch];
    uint32_t u0 = v.x, u1 = v.y, u2 = v.z, u3 = v.w;
    Vt[(ch + 0) * 264 + r] = (ushort)(u0 & 0xffff);
    Vt[(ch + 1) * 264 + r] = (ushort)(u0 >> 16);
    Vt[(ch + 2) * 264 + r] = (ushort)(u1 & 0xffff);
    Vt[(ch + 3) * 264 + r] = (ushort)(u1 >> 16);
    Vt[(ch + 4) * 264 + r] = (ushort)(u2 & 0xffff);
    Vt[(ch + 5) * 264 + r] = (ushort)(u2 >> 16);
    Vt[(ch + 6) * 264 + r] = (ushort)(u3 & 0xffff);
    Vt[(ch + 7) * 264 + r] = (ushort)(u3 >> 16);
  }
  __syncthreads();

  // ---- S = Q K^T for this wave's 64 j columns ----
  const int jw = wave * 64;
  f32x4 zero = {0.f, 0.f, 0.f, 0.f};
  f32x4 acc[4][4];
#pragma unroll
  for (int i = 0; i < 4; ++i)
#pragma unroll
    for (int j = 0; j < 4; ++j) acc[i][j] = zero;

#pragma unroll
  for (int kb = 0; kb < 2; ++kb) {
    bf16x8 af[4], bfv[4];
#pragma unroll
    for (int mi = 0; mi < 4; ++mi)
      af[mi] = ld_frag(&Qs[(mi * 16 + l16) * 72 + kb * 32 + quad * 8]);
#pragma unroll
    for (int mj = 0; mj < 4; ++mj)
      bfv[mj] = ld_frag(&Ks[(jw + mj * 16 + l16) * 72 + kb * 32 + quad * 8]);
#pragma unroll
    for (int mi = 0; mi < 4; ++mi)
#pragma unroll
      for (int mj = 0; mj < 4; ++mj)
        acc[mi][mj] = __builtin_amdgcn_mfma_f32_16x16x32_bf16(af[mi], bfv[mj], acc[mi][mj], 0, 0, 0);
  }
#pragma unroll
  for (int mi = 0; mi < 4; ++mi)
#pragma unroll
    for (int mj = 0; mj < 4; ++mj) acc[mi][mj] = acc[mi][mj] * 0.125f;

  // ---- softmax over 256 (cross-wave via LDS partials) ----
  float rmax[4][4];
#pragma unroll
  for (int mi = 0; mi < 4; ++mi)
#pragma unroll
    for (int rr = 0; rr < 4; ++rr) {
      float m = fmaxf(fmaxf(acc[mi][0][rr], acc[mi][1][rr]),
                      fmaxf(acc[mi][2][rr], acc[mi][3][rr]));
      m = fmaxf(m, __shfl_xor(m, 1));
      m = fmaxf(m, __shfl_xor(m, 2));
      m = fmaxf(m, __shfl_xor(m, 4));
      m = fmaxf(m, __shfl_xor(m, 8));
      rmax[mi][rr] = m;
    }
  if (l16 == 0) {
#pragma unroll
    for (int mi = 0; mi < 4; ++mi)
#pragma unroll
      for (int rr = 0; rr < 4; ++rr)
        redm[wave][mi * 16 + quad * 4 + rr] = rmax[mi][rr];
  }
  __syncthreads();
  float gmax[4][4];
#pragma unroll
  for (int mi = 0; mi < 4; ++mi)
#pragma unroll
    for (int rr = 0; rr < 4; ++rr) {
      const int row = mi * 16 + quad * 4 + rr;
      gmax[mi][rr] = fmaxf(fmaxf(redm[0][row], redm[1][row]),
                           fmaxf(redm[2][row], redm[3][row]));
    }
  float rsum[4][4];
#pragma unroll
  for (int mi = 0; mi < 4; ++mi)
#pragma unroll
    for (int rr = 0; rr < 4; ++rr) {
      float s = 0.f;
#pragma unroll
      for (int mj = 0; mj < 4; ++mj) {
        float p = exp2f((acc[mi][mj][rr] - gmax[mi][rr]) * 1.4426950408889634f);
        acc[mi][mj][rr] = p;
        s += p;
      }
      s += __shfl_xor(s, 1);
      s += __shfl_xor(s, 2);
      s += __shfl_xor(s, 4);
      s += __shfl_xor(s, 8);
      rsum[mi][rr] = s;
    }
  if (l16 == 0) {
#pragma unroll
    for (int mi = 0; mi < 4; ++mi)
#pragma unroll
      for (int rr = 0; rr < 4; ++rr)
        reds[wave][mi * 16 + quad * 4 + rr] = rsum[mi][rr];
  }
  __syncthreads();
  // write normalized P (bf16) to LDS (overlays Qs/Ks — all reads done)
#pragma unroll
  for (int mi = 0; mi < 4; ++mi)
#pragma unroll
    for (int rr = 0; rr < 4; ++rr) {
      const int row = mi * 16 + quad * 4 + rr;
      const float inv = 1.0f / (reds[0][row] + reds[1][row] + reds[2][row] + reds[3][row]);
#pragma unroll
      for (int mj = 0; mj < 4; ++mj)
        Ps[row * 264 + jw + mj * 16 + l16] = f2bf(acc[mi][mj][rr] * inv);
    }
  __syncthreads();

  // ---- O = P V : wave handles d-slice [wave*16, wave*16+16) ----
  const int d0 = wave * 16;
  f32x4 acc2[4];
#pragma unroll
  for (int mi = 0; mi < 4; ++mi) acc2[mi] = zero;
#pragma unroll
  for (int kb = 0; kb < 8; ++kb) {
    bf16x8 bfv = ld_frag(&Vt[(d0 + l16) * 264 + kb * 32 + quad * 8]);
#pragma unroll
    for (int mi = 0; mi < 4; ++mi) {
      bf16x8 af = ld_frag(&Ps[(mi * 16 + l16) * 264 + kb * 32 + quad * 8]);
      acc2[mi] = __builtin_amdgcn_mfma_f32_16x16x32_bf16(af, bfv, acc2[mi], 0, 0, 0);
    }
  }
#pragma unroll
  for (int mi = 0; mi < 4; ++mi)
#pragma unroll
    for (int rr = 0; rr < 4; ++rr) {
      const int i = mi * 16 + quad * 4 + rr;
      Ob[(size_t)(qrow0 + i) * 1024 + colh + d0 + l16] = f2bf(acc2[mi][rr]);
    }
}

// ---------------------------------------------------------------------------
// head rows 0..62 of each batch: pure residual copy
// ---------------------------------------------------------------------------
__global__ __launch_bounds__(256) void head_copy(const float* __restrict__ h,
                                                 float* __restrict__ out) {
  const int idx4 = blockIdx.x * 256 + threadIdx.x;   // 0 .. 64511
  const int b = idx4 / 16128;
  const int rem = idx4 - b * 16128;
  const size_t o = (size_t)b * 2048 * 1024 + (size_t)rem * 4;
  *(float4*)&out[o] = *(const float4*)&h[o];
}

// ---------------------------------------------------------------------------
extern "C" void kernel_launch(void* const* d_in, const int* in_sizes, int n_in,
                              void* d_out, int out_size, void* d_ws, size_t ws_size,
                              hipStream_t stream) {
  const float* h     = (const float*)d_in[0];
  const float* e     = (const float*)d_in[1];
  const float* Wq    = (const float*)d_in[2];
  const float* bq    = (const float*)d_in[3];
  const float* Wk    = (const float*)d_in[4];
  const float* bk    = (const float*)d_in[5];
  const float* Wv    = (const float*)d_in[6];
  const float* bv    = (const float*)d_in[7];
  const float* Wo    = (const float*)d_in[8];
  const float* bo    = (const float*)d_in[9];
  const float* gamma = (const float*)d_in[10];
  const float* beta  = (const float*)d_in[11];
  float* out = (float*)d_out;

  char* ws = (char*)d_ws;                             // total used: 184 MiB
  ushort* WqT = (ushort*)(ws + ((size_t)0 << 20));    // 2 MiB
  ushort* WkT = (ushort*)(ws + ((size_t)2 << 20));    // 2 MiB
  ushort* WvT = (ushort*)(ws + ((size_t)4 << 20));    // 2 MiB
  ushort* WoT = (ushort*)(ws + ((size_t)6 << 20));    // 2 MiB
  ushort* hhb = (ushort*)(ws + ((size_t)8 << 20));    // 16 MiB (LN out; later e-cast quarters)
  ushort* Qb  = (ushort*)(ws + ((size_t)24 << 20));   // 16 MiB
  ushort* Kb  = (ushort*)(ws + ((size_t)40 << 20));   // 64 MiB
  ushort* Vb  = (ushort*)(ws + ((size_t)104 << 20));  // 64 MiB
  ushort* Ob  = (ushort*)(ws + ((size_t)168 << 20));  // 16 MiB

  // 1. weights -> bf16 transposed
  transpose_cast<<<dim3(16, 16), 256, 0, stream>>>(Wq, WqT);
  transpose_cast<<<dim3(16, 16), 256, 0, stream>>>(Wk, WkT);
  transpose_cast<<<dim3(16, 16), 256, 0, stream>>>(Wv, WvT);
  transpose_cast<<<dim3(16, 16), 256, 0, stream>>>(Wo, WoT);

  // 2. LayerNorm -> hh (bf16, padded)
  ln_kernel<<<8192, 256, 0, stream>>>(h, gamma, beta, hhb);

  // 3. Q projection (consumes hhb)
  gemm_bf16<0><<<512, 256, 0, stream>>>(hhb, WqT, bq, Qb, nullptr, nullptr, 64, 0);

  // 4. K/V projections in 4 quarters of 8192 rows, reusing hhb as the
  //    e->bf16 staging buffer (keeps workspace at 184 MiB).
  for (int q = 0; q < 4; ++q) {
    const size_t roff = (size_t)q * 8192 * 1024;
    cast_bf16<<<4096, 256, 0, stream>>>(e + roff, hhb);
    gemm_bf16<0><<<512, 256, 0, stream>>>(hhb, WkT, bk, Kb + roff, nullptr, nullptr, 64, 0);
    gemm_bf16<0><<<512, 256, 0, stream>>>(hhb, WvT, bv, Vb + roff, nullptr, nullptr, 64, 0);
  }

  // 5. attention per (b, chunk, head)
  attn_kernel<<<2048, 256, 0, stream>>>(Qb, Kb, Vb, Ob);

  // 6. output projection + shifted residual (f32 out), plus first-63-row copy
  gemm_bf16<1><<<512, 256, 0, stream>>>(Ob, WoT, bo, nullptr, out, h, 64, 0);
  head_copy<<<252, 256, 0, stream>>>(h, out);
}

// Round 4
// 605.596 us; speedup vs baseline: 1.1808x; 1.0065x over previous
//
#include <hip/hip_runtime.h>
#include <cstdint>
#include <cstddef>

// ---------------------------------------------------------------------------
// ChunkedCrossAttention: h(4,2048,1024), e(4,32,2,128,1024)
// LN(h[:,63:]) -> Q; e -> fused KV GEMM (N=2048, V written pre-transposed
// per head); per-(b,chunk,head) attn over 256 keys; O-proj + residual.
// GEMMs: bf16 MFMA 16x16x32, f32 acc, global_load_lds staging, XCD swizzle.
// Workspace: 184 MiB exactly (proven safe).
// ---------------------------------------------------------------------------

typedef float f32x4 __attribute__((ext_vector_type(4)));
typedef __bf16 bf16x8 __attribute__((ext_vector_type(8)));

static __device__ __forceinline__ ushort f2bf(float f) {
  union { float f; uint32_t u; } x; x.f = f;
  uint32_t r = x.u + 0x7fffu + ((x.u >> 16) & 1u);   // RTNE
  return (ushort)(r >> 16);
}

static __device__ __forceinline__ bf16x8 ld_frag(const ushort* p) {
  union { uint4 u; bf16x8 v; } x;
  x.u = *(const uint4*)p;
  return x.v;
}

// async global->LDS, 16 B per lane (proven working in round 3).
static __device__ __forceinline__ void gl2lds16(const ushort* g, ushort* l) {
  __builtin_amdgcn_global_load_lds(
      (const __attribute__((address_space(1))) void*)g,
      (__attribute__((address_space(3))) void*)l,
      16, 0, 0);
}

// ---------------------------------------------------------------------------
// Weight transpose + cast, all 4 weights in one dispatch (z selects).
// W (1024x1024 f32, KxN) -> WT (NxK bf16). Wk,Wv pack into WkvT[2048][1024].
// ---------------------------------------------------------------------------
__global__ __launch_bounds__(256) void transpose_cast4(const float* __restrict__ Wq,
                                                       const float* __restrict__ Wk,
                                                       const float* __restrict__ Wv,
                                                       const float* __restrict__ Wo,
                                                       ushort* __restrict__ WqT,
                                                       ushort* __restrict__ WkvT,
                                                       ushort* __restrict__ WoT) {
  const float* W; ushort* WT;
  switch (blockIdx.z) {
    case 0:  W = Wq; WT = WqT; break;
    case 1:  W = Wk; WT = WkvT; break;
    case 2:  W = Wv; WT = WkvT + (size_t)1024 * 1024; break;
    default: W = Wo; WT = WoT; break;
  }
  __shared__ float tile[64][65];
  const int t = threadIdx.x;
  const int n0 = blockIdx.x * 64, k0 = blockIdx.y * 64;
#pragma unroll
  for (int i = 0; i < 4; ++i) {
    int lid = i * 256 + t;
    int r = lid >> 4, c4 = (lid & 15) * 4;
    float4 v = *(const float4*)&W[(size_t)(k0 + r) * 1024 + n0 + c4];
    tile[r][c4 + 0] = v.x; tile[r][c4 + 1] = v.y;
    tile[r][c4 + 2] = v.z; tile[r][c4 + 3] = v.w;
  }
  __syncthreads();
#pragma unroll
  for (int i = 0; i < 4; ++i) {
    int lid = i * 256 + t;
    int n = lid >> 4, k4 = (lid & 15) * 4;
    ushort4 o;
    o.x = f2bf(tile[k4 + 0][n]); o.y = f2bf(tile[k4 + 1][n]);
    o.z = f2bf(tile[k4 + 2][n]); o.w = f2bf(tile[k4 + 3][n]);
    *(ushort4*)&WT[(size_t)(n0 + n) * 1024 + k0 + k4] = o;
  }
}

// ---------------------------------------------------------------------------
// cast f32 -> bf16, 8 elems/thread
// ---------------------------------------------------------------------------
__global__ __launch_bounds__(256) void cast_bf16(const float* __restrict__ x,
                                                 ushort* __restrict__ y) {
  const size_t i = ((size_t)blockIdx.x * 256 + threadIdx.x) * 8;
  float4 a = *(const float4*)&x[i];
  float4 b = *(const float4*)&x[i + 4];
  ushort o[8];
  o[0] = f2bf(a.x); o[1] = f2bf(a.y); o[2] = f2bf(a.z); o[3] = f2bf(a.w);
  o[4] = f2bf(b.x); o[5] = f2bf(b.y); o[6] = f2bf(b.z); o[7] = f2bf(b.w);
  *(uint4*)&y[i] = *(const uint4*)o;
}

// ---------------------------------------------------------------------------
// LayerNorm: hh[b, s, :] = LN(h[b, 63+s, :]) for s<1985 else 0   (bf16 out)
// ---------------------------------------------------------------------------
__global__ __launch_bounds__(256) void ln_kernel(const float* __restrict__ h,
                                                 const float* __restrict__ gamma,
                                                 const float* __restrict__ beta,
                                                 ushort* __restrict__ hh) {
  const int bx = blockIdx.x;
  const int b = bx >> 11, s = bx & 2047;
  const int t = threadIdx.x;
  ushort* orow = hh + (size_t)(b * 2048 + s) * 1024;
  if (s >= 1985) {
    ushort4 z; z.x = 0; z.y = 0; z.z = 0; z.w = 0;
    *(ushort4*)&orow[t * 4] = z;
    return;
  }
  const float* xrow = h + (size_t)(b * 2048 + 63 + s) * 1024;
  float4 x = *(const float4*)&xrow[t * 4];
  float s1 = x.x + x.y + x.z + x.w;
  float s2 = x.x * x.x + x.y * x.y + x.z * x.z + x.w * x.w;
#pragma unroll
  for (int off = 32; off > 0; off >>= 1) {
    s1 += __shfl_xor(s1, off);
    s2 += __shfl_xor(s2, off);
  }
  __shared__ float a1[4], a2[4];
  if ((t & 63) == 0) { a1[t >> 6] = s1; a2[t >> 6] = s2; }
  __syncthreads();
  s1 = a1[0] + a1[1] + a1[2] + a1[3];
  s2 = a2[0] + a2[1] + a2[2] + a2[3];
  const float mu = s1 * (1.0f / 1024.0f);
  const float var = s2 * (1.0f / 1024.0f) - mu * mu;
  const float rstd = rsqrtf(var + 1e-5f);
  float4 g = *(const float4*)&gamma[t * 4];
  float4 be = *(const float4*)&beta[t * 4];
  ushort4 o;
  o.x = f2bf((x.x - mu) * rstd * g.x + be.x);
  o.y = f2bf((x.y - mu) * rstd * g.y + be.y);
  o.z = f2bf((x.z - mu) * rstd * g.z + be.z);
  o.w = f2bf((x.w - mu) * rstd * g.w + be.w);
  *(ushort4*)&orow[t * 4] = o;
}

// ---------------------------------------------------------------------------
// GEMM (m97-style): C[M,N] = A[M,1024](bf16) @ Bt[N,1024]^T(bf16) + bias
//  MODE 0 (NT=8):  C -> bf16 row-major, post-scale (used for Q, scale=1/8)
//  MODE 2 (NT=16): fused KV. nt<8: K -> row-major bf16 [r][cc] (bias=bk).
//                  nt>=8: V -> transposed per head: Vtg[(r>>8)*16+h][d][j]
//                  (bias2=bv), ushort4 packs over the 4 j-consecutive accs.
//  MODE 1 (NT=8):  f32 out with shifted residual add (O-proj).
// 128x128 tile, BK=32, 4 waves, global_load_lds x16, XCD-aware swizzle.
// ---------------------------------------------------------------------------
template <int MODE, int NT>
__global__ __launch_bounds__(256) void gemm_bf16(const ushort* __restrict__ A,
                                                 const ushort* __restrict__ Bt,
                                                 const float* __restrict__ bias,
                                                 const float* __restrict__ bias2,
                                                 ushort* __restrict__ Cbf,
                                                 ushort* __restrict__ Vtg,
                                                 float* __restrict__ Cf,
                                                 const float* __restrict__ resid,
                                                 int mtiles, float scale) {
  __shared__ __align__(16) ushort Alds[128 * 32];
  __shared__ __align__(16) ushort Blds[128 * 32];
  const int t = threadIdx.x;
  const int lane = t & 63, wave = t >> 6;
  const int quad = lane >> 4, l16 = lane & 15;

  // XCD swizzle: each XCD (L%8) owns a contiguous M-range x all NT N-tiles.
  const int L = blockIdx.x;
  const int xcd = L & 7, slot = L >> 3;
  const int nt = slot & (NT - 1);
  const int mt = xcd * (mtiles >> 3) + (slot / NT);
  const int m0 = mt * 128, n0 = nt * 128;

  // staging: 8 chunks of 16 rows x 32 cols per tile; wave w does chunks 2w,2w+1
  const int srow = lane >> 2;          // 0..15
  const int scol = (lane & 3) * 8;     // 0,8,16,24
  const int c0 = wave * 2;
  const ushort* gA0 = A  + (size_t)(m0 + c0 * 16 + srow) * 1024 + scol;
  const ushort* gA1 = gA0 + 16 * 1024;
  const ushort* gB0 = Bt + (size_t)(n0 + c0 * 16 + srow) * 1024 + scol;
  const ushort* gB1 = gB0 + 16 * 1024;
  ushort* dA0 = &Alds[c0 * 512 + lane * 8];
  ushort* dA1 = dA0 + 512;
  ushort* dB0 = &Blds[c0 * 512 + lane * 8];
  ushort* dB1 = dB0 + 512;

  const int wrow = (wave >> 1) * 64, wcol = (wave & 1) * 64;
  const ushort* pA = &Alds[(wrow + l16) * 32 + quad * 8];
  const ushort* pB = &Blds[(wcol + l16) * 32 + quad * 8];

  f32x4 zero = {0.f, 0.f, 0.f, 0.f};
  f32x4 acc[4][4];
#pragma unroll
  for (int i = 0; i < 4; ++i)
#pragma unroll
    for (int j = 0; j < 4; ++j) acc[i][j] = zero;

  for (int kb = 0; kb < 32; ++kb) {
    const int ko = kb * 32;
    gl2lds16(gA0 + ko, dA0);
    gl2lds16(gA1 + ko, dA1);
    gl2lds16(gB0 + ko, dB0);
    gl2lds16(gB1 + ko, dB1);
    __syncthreads();
    bf16x8 af[4], bfv[4];
#pragma unroll
    for (int i = 0; i < 4; ++i) af[i]  = ld_frag(pA + i * 16 * 32);
#pragma unroll
    for (int j = 0; j < 4; ++j) bfv[j] = ld_frag(pB + j * 16 * 32);
#pragma unroll
    for (int i = 0; i < 4; ++i)
#pragma unroll
      for (int j = 0; j < 4; ++j)
        acc[i][j] = __builtin_amdgcn_mfma_f32_16x16x32_bf16(af[i], bfv[j], acc[i][j], 0, 0, 0);
    __syncthreads();
  }

#pragma unroll
  for (int mi = 0; mi < 4; ++mi)
#pragma unroll
    for (int mj = 0; mj < 4; ++mj) {
      const int cc = n0 + wcol + mj * 16 + l16;
      const int r0 = m0 + wrow + mi * 16 + quad * 4;
      if constexpr (MODE == 0) {
        const float bvb = bias[cc];
#pragma unroll
        for (int rr = 0; rr < 4; ++rr)
          Cbf[(size_t)(r0 + rr) * 1024 + cc] = f2bf((acc[mi][mj][rr] + bvb) * scale);
      } else if constexpr (MODE == 2) {
        if (nt < 8) {   // K: row-major
          const float bvb = bias[cc];
#pragma unroll
          for (int rr = 0; rr < 4; ++rr)
            Cbf[(size_t)(r0 + rr) * 1024 + cc] = f2bf(acc[mi][mj][rr] + bvb);
        } else {        // V: transposed per head, ushort4 over j
          const int cv = cc - 1024;
          const int hh_ = cv >> 6, dd = cv & 63;
          const float bvb = bias2[cv];
          const int bcl = r0 >> 8, j0 = r0 & 255;
          ushort4 o;
          o.x = f2bf(acc[mi][mj][0] + bvb);
          o.y = f2bf(acc[mi][mj][1] + bvb);
          o.z = f2bf(acc[mi][mj][2] + bvb);
          o.w = f2bf(acc[mi][mj][3] + bvb);
          *(ushort4*)&Vtg[((size_t)(bcl * 16 + hh_)) * 16384 + dd * 256 + j0] = o;
        }
      } else {          // MODE 1: f32 out + shifted residual
        const float bvb = bias[cc];
#pragma unroll
        for (int rr = 0; rr < 4; ++rr) {
          const int r = r0 + rr;
          const int b = r >> 11, s = r & 2047;
          if (s < 1985) {
            const size_t o = (size_t)(b * 2048 + s + 63) * 1024 + cc;
            Cf[o] = acc[mi][mj][rr] + bvb + resid[o];
          }
        }
      }
    }
}

// ---------------------------------------------------------------------------
// Attention: one block per (b, chunk, head). 256 threads (4 waves).
// V arrives pre-transposed ([bch][d][j]) -> clean uint4 staging.
// Scale 1/8 is pre-folded into Q. LDS overlay -> ~80 KiB, 2 blocks/CU.
// ---------------------------------------------------------------------------
__global__ __launch_bounds__(256) void attn_kernel(const ushort* __restrict__ Qb,
                                                   const ushort* __restrict__ Kb,
                                                   const ushort* __restrict__ Vtg,
                                                   ushort* __restrict__ Ob) {
  // Qs: 64x72 (4608) | Ks: 256x72 (18432) | Vt: 64x264 (16896)  [elems]
  // Ps: 64x264 (16896) overlays Qs+Ks (23040)
  __shared__ __align__(16) ushort smem[4608 + 18432 + 16896];   // 79872 B
  __shared__ float redm[4][64];
  __shared__ float reds[4][64];
  ushort* Qs = smem;
  ushort* Ks = smem + 4608;
  ushort* Vt = smem + 23040;
  ushort* Ps = smem;

  const int t = threadIdx.x;
  const int bx = blockIdx.x;
  const int hd = bx & 15, c = (bx >> 4) & 31, b = bx >> 9;
  const int lane = t & 63, wave = t >> 6;
  const int quad = lane >> 4, l16 = lane & 15;

  const int qrow0 = b * 2048 + c * 64;
  const int kvrow0 = (b * 32 + c) * 256;
  const int colh = hd * 64;
  const ushort* vsrc = Vtg + ((size_t)((b * 32 + c) * 16 + hd)) * 16384;

  // load Q (64 x 64)
#pragma unroll
  for (int it = 0; it < 2; ++it) {
    int lid = it * 256 + t;
    int r = lid >> 3, ch = (lid & 7) * 8;
    uint4 v = *(const uint4*)&Qb[(size_t)(qrow0 + r) * 1024 + colh + ch];
    *(uint4*)&Qs[r * 72 + ch] = v;
  }
  // load K (256 x 64)
#pragma unroll
  for (int it = 0; it < 8; ++it) {
    int lid = it * 256 + t;
    int r = lid >> 3, ch = (lid & 7) * 8;
    uint4 v = *(const uint4*)&Kb[(size_t)(kvrow0 + r) * 1024 + colh + ch];
    *(uint4*)&Ks[r * 72 + ch] = v;
  }
  // load V (already [d=64][j=256]) -> Vt stride 264
#pragma unroll
  for (int it = 0; it < 8; ++it) {
    int lid = it * 256 + t;
    int row = lid >> 5, c8 = (lid & 31) * 8;
    uint4 v = *(const uint4*)&vsrc[row * 256 + c8];
    *(uint4*)&Vt[row * 264 + c8] = v;
  }
  __syncthreads();

  // ---- S = Q K^T for this wave's 64 j columns (Q pre-scaled by 1/8) ----
  const int jw = wave * 64;
  f32x4 zero = {0.f, 0.f, 0.f, 0.f};
  f32x4 acc[4][4];
#pragma unroll
  for (int i = 0; i < 4; ++i)
#pragma unroll
    for (int j = 0; j < 4; ++j) acc[i][j] = zero;

#pragma unroll
  for (int kb = 0; kb < 2; ++kb) {
    bf16x8 af[4], bfv[4];
#pragma unroll
    for (int mi = 0; mi < 4; ++mi)
      af[mi] = ld_frag(&Qs[(mi * 16 + l16) * 72 + kb * 32 + quad * 8]);
#pragma unroll
    for (int mj = 0; mj < 4; ++mj)
      bfv[mj] = ld_frag(&Ks[(jw + mj * 16 + l16) * 72 + kb * 32 + quad * 8]);
#pragma unroll
    for (int mi = 0; mi < 4; ++mi)
#pragma unroll
      for (int mj = 0; mj < 4; ++mj)
        acc[mi][mj] = __builtin_amdgcn_mfma_f32_16x16x32_bf16(af[mi], bfv[mj], acc[mi][mj], 0, 0, 0);
  }

  // ---- softmax over 256 (cross-wave via LDS partials) ----
  float rmax[4][4];
#pragma unroll
  for (int mi = 0; mi < 4; ++mi)
#pragma unroll
    for (int rr = 0; rr < 4; ++rr) {
      float m = fmaxf(fmaxf(acc[mi][0][rr], acc[mi][1][rr]),
                      fmaxf(acc[mi][2][rr], acc[mi][3][rr]));
      m = fmaxf(m, __shfl_xor(m, 1));
      m = fmaxf(m, __shfl_xor(m, 2));
      m = fmaxf(m, __shfl_xor(m, 4));
      m = fmaxf(m, __shfl_xor(m, 8));
      rmax[mi][rr] = m;
    }
  if (l16 == 0) {
#pragma unroll
    for (int mi = 0; mi < 4; ++mi)
#pragma unroll
      for (int rr = 0; rr < 4; ++rr)
        redm[wave][mi * 16 + quad * 4 + rr] = rmax[mi][rr];
  }
  __syncthreads();
  float gmax[4][4];
#pragma unroll
  for (int mi = 0; mi < 4; ++mi)
#pragma unroll
    for (int rr = 0; rr < 4; ++rr) {
      const int row = mi * 16 + quad * 4 + rr;
      gmax[mi][rr] = fmaxf(fmaxf(redm[0][row], redm[1][row]),
                           fmaxf(redm[2][row], redm[3][row]));
    }
  float rsum[4][4];
#pragma unroll
  for (int mi = 0; mi < 4; ++mi)
#pragma unroll
    for (int rr = 0; rr < 4; ++rr) {
      float s = 0.f;
#pragma unroll
      for (int mj = 0; mj < 4; ++mj) {
        float p = exp2f((acc[mi][mj][rr] - gmax[mi][rr]) * 1.4426950408889634f);
        acc[mi][mj][rr] = p;
        s += p;
      }
      s += __shfl_xor(s, 1);
      s += __shfl_xor(s, 2);
      s += __shfl_xor(s, 4);
      s += __shfl_xor(s, 8);
      rsum[mi][rr] = s;
    }
  if (l16 == 0) {
#pragma unroll
    for (int mi = 0; mi < 4; ++mi)
#pragma unroll
      for (int rr = 0; rr < 4; ++rr)
        reds[wave][mi * 16 + quad * 4 + rr] = rsum[mi][rr];
  }
  __syncthreads();
  // write normalized P (bf16) to LDS (overlays Qs/Ks — all reads done)
#pragma unroll
  for (int mi = 0; mi < 4; ++mi)
#pragma unroll
    for (int rr = 0; rr < 4; ++rr) {
      const int row = mi * 16 + quad * 4 + rr;
      const float inv = 1.0f / (reds[0][row] + reds[1][row] + reds[2][row] + reds[3][row]);
#pragma unroll
      for (int mj = 0; mj < 4; ++mj)
        Ps[row * 264 + jw + mj * 16 + l16] = f2bf(acc[mi][mj][rr] * inv);
    }
  __syncthreads();

  // ---- O = P V : wave handles d-slice [wave*16, wave*16+16) ----
  const int d0 = wave * 16;
  f32x4 acc2[4];
#pragma unroll
  for (int mi = 0; mi < 4; ++mi) acc2[mi] = zero;
#pragma unroll
  for (int kb = 0; kb < 8; ++kb) {
    bf16x8 bfv = ld_frag(&Vt[(d0 + l16) * 264 + kb * 32 + quad * 8]);
#pragma unroll
    for (int mi = 0; mi < 4; ++mi) {
      bf16x8 af = ld_frag(&Ps[(mi * 16 + l16) * 264 + kb * 32 + quad * 8]);
      acc2[mi] = __builtin_amdgcn_mfma_f32_16x16x32_bf16(af, bfv, acc2[mi], 0, 0, 0);
    }
  }
#pragma unroll
  for (int mi = 0; mi < 4; ++mi)
#pragma unroll
    for (int rr = 0; rr < 4; ++rr) {
      const int i = mi * 16 + quad * 4 + rr;
      Ob[(size_t)(qrow0 + i) * 1024 + colh + d0 + l16] = f2bf(acc2[mi][rr]);
    }
}

// ---------------------------------------------------------------------------
// head rows 0..62 of each batch: pure residual copy
// ---------------------------------------------------------------------------
__global__ __launch_bounds__(256) void head_copy(const float* __restrict__ h,
                                                 float* __restrict__ out) {
  const int idx4 = blockIdx.x * 256 + threadIdx.x;   // 0 .. 64511
  const int b = idx4 / 16128;
  const int rem = idx4 - b * 16128;
  const size_t o = (size_t)b * 2048 * 1024 + (size_t)rem * 4;
  *(float4*)&out[o] = *(const float4*)&h[o];
}

// ---------------------------------------------------------------------------
extern "C" void kernel_launch(void* const* d_in, const int* in_sizes, int n_in,
                              void* d_out, int out_size, void* d_ws, size_t ws_size,
                              hipStream_t stream) {
  const float* h     = (const float*)d_in[0];
  const float* e     = (const float*)d_in[1];
  const float* Wq    = (const float*)d_in[2];
  const float* bq    = (const float*)d_in[3];
  const float* Wk    = (const float*)d_in[4];
  const float* bk    = (const float*)d_in[5];
  const float* Wv    = (const float*)d_in[6];
  const float* bv    = (const float*)d_in[7];
  const float* Wo    = (const float*)d_in[8];
  const float* bo    = (const float*)d_in[9];
  const float* gamma = (const float*)d_in[10];
  const float* beta  = (const float*)d_in[11];
  float* out = (float*)d_out;

  char* ws = (char*)d_ws;                              // total used: 184 MiB
  ushort* WqT  = (ushort*)(ws + ((size_t)0 << 20));    // 2 MiB
  ushort* WkvT = (ushort*)(ws + ((size_t)2 << 20));    // 4 MiB (Wk | Wv)
  ushort* WoT  = (ushort*)(ws + ((size_t)6 << 20));    // 2 MiB
  ushort* hhb  = (ushort*)(ws + ((size_t)8 << 20));    // 16 MiB (LN out; then e-cast quarters)
  ushort* Qb   = (ushort*)(ws + ((size_t)24 << 20));   // 16 MiB
  ushort* Kb   = (ushort*)(ws + ((size_t)40 << 20));   // 64 MiB
  ushort* VtG  = (ushort*)(ws + ((size_t)104 << 20));  // 64 MiB ([bch][64][256])
  ushort* Ob   = (ushort*)(ws + ((size_t)168 << 20));  // 16 MiB

  // 1. weights -> bf16 transposed (one dispatch)
  transpose_cast4<<<dim3(16, 16, 4), 256, 0, stream>>>(Wq, Wk, Wv, Wo, WqT, WkvT, WoT);

  // 2. LayerNorm -> hh (bf16, padded)
  ln_kernel<<<8192, 256, 0, stream>>>(h, gamma, beta, hhb);

  // 3. Q projection (scale 1/8 folded in; consumes hhb)
  gemm_bf16<0, 8><<<512, 256, 0, stream>>>(hhb, WqT, bq, nullptr, Qb, nullptr,
                                           nullptr, nullptr, 64, 0.125f);

  // 4. fused K|V projection in 4 quarters of 8192 rows (e cast through hhb).
  //    V is written pre-transposed per (b,c,head).
  for (int q = 0; q < 4; ++q) {
    const size_t roff = (size_t)q * 8192 * 1024;
    cast_bf16<<<4096, 256, 0, stream>>>(e + roff, hhb);
    gemm_bf16<2, 16><<<1024, 256, 0, stream>>>(hhb, WkvT, bk, bv, Kb + roff,
                                               VtG + roff, nullptr, nullptr, 64, 1.0f);
  }

  // 5. attention per (b, chunk, head)
  attn_kernel<<<2048, 256, 0, stream>>>(Qb, Kb, VtG, Ob);

  // 6. output projection + shifted residual (f32 out), plus first-63-row copy
  gemm_bf16<1, 8><<<512, 256, 0, stream>>>(Ob, WoT, bo, nullptr, nullptr, nullptr,
                                           out, h, 64, 1.0f);
  head_copy<<<252, 256, 0, stream>>>(h, out);
}

// Round 5
// 566.315 us; speedup vs baseline: 1.2627x; 1.0694x over previous
//
#include <hip/hip_runtime.h>
#include <cstdint>
#include <cstddef>

// ---------------------------------------------------------------------------
// ChunkedCrossAttention: h(4,2048,1024), e(4,32,2,128,1024)
// LN(h[:,63:]) -> Q; e -> fused KV GEMM (N=2048, V pre-transposed per head);
// per-(b,chunk,head) attn over 256 keys; O-proj + shifted residual.
// GEMMs: bf16 MFMA 16x16x32, f32 acc, global_load_lds staging, BK=64 as two
// proven BK=32 sub-tiles, XCD swizzle. Workspace exactly 184 MiB.
// ---------------------------------------------------------------------------

typedef float f32x4 __attribute__((ext_vector_type(4)));
typedef __bf16 bf16x8 __attribute__((ext_vector_type(8)));

static __device__ __forceinline__ ushort f2bf(float f) {
  union { float f; uint32_t u; } x; x.f = f;
  uint32_t r = x.u + 0x7fffu + ((x.u >> 16) & 1u);   // RTNE
  return (ushort)(r >> 16);
}

static __device__ __forceinline__ bf16x8 ld_frag(const ushort* p) {
  union { uint4 u; bf16x8 v; } x;
  x.u = *(const uint4*)p;
  return x.v;
}

// async global->LDS, 16 B per lane (proven working rounds 3-4).
static __device__ __forceinline__ void gl2lds16(const ushort* g, ushort* l) {
  __builtin_amdgcn_global_load_lds(
      (const __attribute__((address_space(1))) void*)g,
      (__attribute__((address_space(3))) void*)l,
      16, 0, 0);
}

// ---------------------------------------------------------------------------
// Weight transpose + cast, all 4 weights in one dispatch (z selects).
// W (1024x1024 f32, KxN) -> WT (NxK bf16). Wk,Wv pack into WkvT[2048][1024].
// ---------------------------------------------------------------------------
__global__ __launch_bounds__(256) void transpose_cast4(const float* __restrict__ Wq,
                                                       const float* __restrict__ Wk,
                                                       const float* __restrict__ Wv,
                                                       const float* __restrict__ Wo,
                                                       ushort* __restrict__ WqT,
                                                       ushort* __restrict__ WkvT,
                                                       ushort* __restrict__ WoT) {
  const float* W; ushort* WT;
  switch (blockIdx.z) {
    case 0:  W = Wq; WT = WqT; break;
    case 1:  W = Wk; WT = WkvT; break;
    case 2:  W = Wv; WT = WkvT + (size_t)1024 * 1024; break;
    default: W = Wo; WT = WoT; break;
  }
  __shared__ float tile[64][65];
  const int t = threadIdx.x;
  const int n0 = blockIdx.x * 64, k0 = blockIdx.y * 64;
#pragma unroll
  for (int i = 0; i < 4; ++i) {
    int lid = i * 256 + t;
    int r = lid >> 4, c4 = (lid & 15) * 4;
    float4 v = *(const float4*)&W[(size_t)(k0 + r) * 1024 + n0 + c4];
    tile[r][c4 + 0] = v.x; tile[r][c4 + 1] = v.y;
    tile[r][c4 + 2] = v.z; tile[r][c4 + 3] = v.w;
  }
  __syncthreads();
#pragma unroll
  for (int i = 0; i < 4; ++i) {
    int lid = i * 256 + t;
    int n = lid >> 4, k4 = (lid & 15) * 4;
    ushort4 o;
    o.x = f2bf(tile[k4 + 0][n]); o.y = f2bf(tile[k4 + 1][n]);
    o.z = f2bf(tile[k4 + 2][n]); o.w = f2bf(tile[k4 + 3][n]);
    *(ushort4*)&WT[(size_t)(n0 + n) * 1024 + k0 + k4] = o;
  }
}

// ---------------------------------------------------------------------------
// cast f32 -> bf16, 8 elems/thread
// ---------------------------------------------------------------------------
__global__ __launch_bounds__(256) void cast_bf16(const float* __restrict__ x,
                                                 ushort* __restrict__ y) {
  const size_t i = ((size_t)blockIdx.x * 256 + threadIdx.x) * 8;
  float4 a = *(const float4*)&x[i];
  float4 b = *(const float4*)&x[i + 4];
  ushort o[8];
  o[0] = f2bf(a.x); o[1] = f2bf(a.y); o[2] = f2bf(a.z); o[3] = f2bf(a.w);
  o[4] = f2bf(b.x); o[5] = f2bf(b.y); o[6] = f2bf(b.z); o[7] = f2bf(b.w);
  *(uint4*)&y[i] = *(const uint4*)o;
}

// ---------------------------------------------------------------------------
// LayerNorm: hh[b, s, :] = LN(h[b, 63+s, :]) for s<1985 else 0   (bf16 out)
// ---------------------------------------------------------------------------
__global__ __launch_bounds__(256) void ln_kernel(const float* __restrict__ h,
                                                 const float* __restrict__ gamma,
                                                 const float* __restrict__ beta,
                                                 ushort* __restrict__ hh) {
  const int bx = blockIdx.x;
  const int b = bx >> 11, s = bx & 2047;
  const int t = threadIdx.x;
  ushort* orow = hh + (size_t)(b * 2048 + s) * 1024;
  if (s >= 1985) {
    ushort4 z; z.x = 0; z.y = 0; z.z = 0; z.w = 0;
    *(ushort4*)&orow[t * 4] = z;
    return;
  }
  const float* xrow = h + (size_t)(b * 2048 + 63 + s) * 1024;
  float4 x = *(const float4*)&xrow[t * 4];
  float s1 = x.x + x.y + x.z + x.w;
  float s2 = x.x * x.x + x.y * x.y + x.z * x.z + x.w * x.w;
#pragma unroll
  for (int off = 32; off > 0; off >>= 1) {
    s1 += __shfl_xor(s1, off);
    s2 += __shfl_xor(s2, off);
  }
  __shared__ float a1[4], a2[4];
  if ((t & 63) == 0) { a1[t >> 6] = s1; a2[t >> 6] = s2; }
  __syncthreads();
  s1 = a1[0] + a1[1] + a1[2] + a1[3];
  s2 = a2[0] + a2[1] + a2[2] + a2[3];
  const float mu = s1 * (1.0f / 1024.0f);
  const float var = s2 * (1.0f / 1024.0f) - mu * mu;
  const float rstd = rsqrtf(var + 1e-5f);
  float4 g = *(const float4*)&gamma[t * 4];
  float4 be = *(const float4*)&beta[t * 4];
  ushort4 o;
  o.x = f2bf((x.x - mu) * rstd * g.x + be.x);
  o.y = f2bf((x.y - mu) * rstd * g.y + be.y);
  o.z = f2bf((x.z - mu) * rstd * g.z + be.z);
  o.w = f2bf((x.w - mu) * rstd * g.w + be.w);
  *(ushort4*)&orow[t * 4] = o;
}

// ---------------------------------------------------------------------------
// GEMM: C[M,N] = A[M,1024](bf16) @ Bt[N,1024]^T(bf16) + bias
//  MODE 0 (NT=8):  C -> bf16 row-major, post-scale (Q, scale=1/8)
//  MODE 2 (NT=16): fused KV. nt<8: K row-major (bias=bk). nt>=8: V transposed
//                  per head: Vtg[(gr>>8)*16+h][d][j] (bias2=bv).
//  MODE 1 (NT=8):  f32 out with shifted residual add (O-proj).
// 128x128 tile, BK=64 as two BK=32 sub-tiles (proven 64B-row-stride layout),
// 4 waves, global_load_lds x16, XCD-aware swizzle. 16 barrier-pairs.
// ---------------------------------------------------------------------------
template <int MODE, int NT>
__global__ __launch_bounds__(256) void gemm_bf16(const ushort* __restrict__ A,
                                                 const ushort* __restrict__ Bt,
                                                 const float* __restrict__ bias,
                                                 const float* __restrict__ bias2,
                                                 ushort* __restrict__ Cbf,
                                                 ushort* __restrict__ Vtg,
                                                 float* __restrict__ Cf,
                                                 const float* __restrict__ resid,
                                                 int mtiles, float scale,
                                                 int mrow_off) {
  __shared__ __align__(16) ushort Alds[2][128 * 32];
  __shared__ __align__(16) ushort Blds[2][128 * 32];
  const int t = threadIdx.x;
  const int lane = t & 63, wave = t >> 6;
  const int quad = lane >> 4, l16 = lane & 15;

  // XCD swizzle: each XCD (L%8) owns a contiguous M-range x all NT N-tiles.
  const int L = blockIdx.x;
  const int xcd = L & 7, slot = L >> 3;
  const int nt = slot & (NT - 1);
  const int mt = xcd * (mtiles >> 3) + (slot / NT);
  const int m0 = mt * 128, n0 = nt * 128;

  // staging: per 32-col sub-tile, 8 chunks of 16 rows; wave w does chunks
  // 2w, 2w+1 of BOTH sub-tiles (8 global_load_lds per wave per K-iter).
  const int srow = lane >> 2;          // 0..15
  const int scol = (lane & 3) * 8;     // 0,8,16,24
  const int c0 = wave * 2;
  const ushort* gA0 = A  + (size_t)(m0 + c0 * 16 + srow) * 1024 + scol;
  const ushort* gA1 = gA0 + 16 * 1024;
  const ushort* gB0 = Bt + (size_t)(n0 + c0 * 16 + srow) * 1024 + scol;
  const ushort* gB1 = gB0 + 16 * 1024;
  ushort* dA0 = &Alds[0][c0 * 512 + lane * 8];
  ushort* dA1 = dA0 + 512;
  ushort* dB0 = &Blds[0][c0 * 512 + lane * 8];
  ushort* dB1 = dB0 + 512;
  const ptrdiff_t SUB = 128 * 32;      // LDS offset between sub-tiles

  const int wrow = (wave >> 1) * 64, wcol = (wave & 1) * 64;
  const ushort* pA = &Alds[0][(wrow + l16) * 32 + quad * 8];
  const ushort* pB = &Blds[0][(wcol + l16) * 32 + quad * 8];

  f32x4 zero = {0.f, 0.f, 0.f, 0.f};
  f32x4 acc[4][4];
#pragma unroll
  for (int i = 0; i < 4; ++i)
#pragma unroll
    for (int j = 0; j < 4; ++j) acc[i][j] = zero;

  for (int kb = 0; kb < 16; ++kb) {
    const int ko = kb * 64;
    gl2lds16(gA0 + ko, dA0);         gl2lds16(gA1 + ko, dA1);
    gl2lds16(gA0 + ko + 32, dA0 + SUB); gl2lds16(gA1 + ko + 32, dA1 + SUB);
    gl2lds16(gB0 + ko, dB0);         gl2lds16(gB1 + ko, dB1);
    gl2lds16(gB0 + ko + 32, dB0 + SUB); gl2lds16(gB1 + ko + 32, dB1 + SUB);
    __syncthreads();
#pragma unroll
    for (int sub = 0; sub < 2; ++sub) {
      bf16x8 af[4], bfv[4];
#pragma unroll
      for (int i = 0; i < 4; ++i) af[i]  = ld_frag(pA + sub * SUB + i * 512);
#pragma unroll
      for (int j = 0; j < 4; ++j) bfv[j] = ld_frag(pB + sub * SUB + j * 512);
#pragma unroll
      for (int i = 0; i < 4; ++i)
#pragma unroll
        for (int j = 0; j < 4; ++j)
          acc[i][j] = __builtin_amdgcn_mfma_f32_16x16x32_bf16(af[i], bfv[j], acc[i][j], 0, 0, 0);
    }
    __syncthreads();
  }

#pragma unroll
  for (int mi = 0; mi < 4; ++mi)
#pragma unroll
    for (int mj = 0; mj < 4; ++mj) {
      const int cc = n0 + wcol + mj * 16 + l16;
      const int r0 = m0 + wrow + mi * 16 + quad * 4;
      if constexpr (MODE == 0) {
        const float bvb = bias[cc];
#pragma unroll
        for (int rr = 0; rr < 4; ++rr)
          Cbf[(size_t)(r0 + rr) * 1024 + cc] = f2bf((acc[mi][mj][rr] + bvb) * scale);
      } else if constexpr (MODE == 2) {
        if (nt < 8) {   // K: row-major (Cbf pre-offset for this half)
          const float bvb = bias[cc];
#pragma unroll
          for (int rr = 0; rr < 4; ++rr)
            Cbf[(size_t)(r0 + rr) * 1024 + cc] = f2bf(acc[mi][mj][rr] + bvb);
        } else {        // V: transposed per head, ushort4 over 4 j-rows
          const int cv = cc - 1024;
          const int hh_ = cv >> 6, dd = cv & 63;
          const float bvb = bias2[cv];
          const int gr0 = r0 + mrow_off;
          const int bcl = gr0 >> 8, j0 = gr0 & 255;
          ushort4 o;
          o.x = f2bf(acc[mi][mj][0] + bvb);
          o.y = f2bf(acc[mi][mj][1] + bvb);
          o.z = f2bf(acc[mi][mj][2] + bvb);
          o.w = f2bf(acc[mi][mj][3] + bvb);
          *(ushort4*)&Vtg[((size_t)(bcl * 16 + hh_)) * 16384 + dd * 256 + j0] = o;
        }
      } else {          // MODE 1: f32 out + shifted residual
        const float bvb = bias[cc];
#pragma unroll
        for (int rr = 0; rr < 4; ++rr) {
          const int r = r0 + rr;
          const int b = r >> 11, s = r & 2047;
          if (s < 1985) {
            const size_t o = (size_t)(b * 2048 + s + 63) * 1024 + cc;
            Cf[o] = acc[mi][mj][rr] + bvb + resid[o];
          }
        }
      }
    }
}

// ---------------------------------------------------------------------------
// Attention: one block per (b, chunk, head). 256 threads (4 waves).
// V arrives pre-transposed ([bch][d][j]); scale folded into Q.
// LDS overlay -> ~80 KiB, 2 blocks/CU.
// ---------------------------------------------------------------------------
__global__ __launch_bounds__(256) void attn_kernel(const ushort* __restrict__ Qb,
                                                   const ushort* __restrict__ Kb,
                                                   const ushort* __restrict__ Vtg,
                                                   ushort* __restrict__ Ob) {
  __shared__ __align__(16) ushort smem[4608 + 18432 + 16896];   // 79872 B
  __shared__ float redm[4][64];
  __shared__ float reds[4][64];
  ushort* Qs = smem;
  ushort* Ks = smem + 4608;
  ushort* Vt = smem + 23040;
  ushort* Ps = smem;

  const int t = threadIdx.x;
  const int bx = blockIdx.x;
  const int hd = bx & 15, c = (bx >> 4) & 31, b = bx >> 9;
  const int lane = t & 63, wave = t >> 6;
  const int quad = lane >> 4, l16 = lane & 15;

  const int qrow0 = b * 2048 + c * 64;
  const int kvrow0 = (b * 32 + c) * 256;
  const int colh = hd * 64;
  const ushort* vsrc = Vtg + ((size_t)((b * 32 + c) * 16 + hd)) * 16384;

#pragma unroll
  for (int it = 0; it < 2; ++it) {
    int lid = it * 256 + t;
    int r = lid >> 3, ch = (lid & 7) * 8;
    uint4 v = *(const uint4*)&Qb[(size_t)(qrow0 + r) * 1024 + colh + ch];
    *(uint4*)&Qs[r * 72 + ch] = v;
  }
#pragma unroll
  for (int it = 0; it < 8; ++it) {
    int lid = it * 256 + t;
    int r = lid >> 3, ch = (lid & 7) * 8;
    uint4 v = *(const uint4*)&Kb[(size_t)(kvrow0 + r) * 1024 + colh + ch];
    *(uint4*)&Ks[r * 72 + ch] = v;
  }
#pragma unroll
  for (int it = 0; it < 8; ++it) {
    int lid = it * 256 + t;
    int row = lid >> 5, c8 = (lid & 31) * 8;
    uint4 v = *(const uint4*)&vsrc[row * 256 + c8];
    *(uint4*)&Vt[row * 264 + c8] = v;
  }
  __syncthreads();

  // ---- S = Q K^T for this wave's 64 j columns (Q pre-scaled by 1/8) ----
  const int jw = wave * 64;
  f32x4 zero = {0.f, 0.f, 0.f, 0.f};
  f32x4 acc[4][4];
#pragma unroll
  for (int i = 0; i < 4; ++i)
#pragma unroll
    for (int j = 0; j < 4; ++j) acc[i][j] = zero;

#pragma unroll
  for (int kb = 0; kb < 2; ++kb) {
    bf16x8 af[4], bfv[4];
#pragma unroll
    for (int mi = 0; mi < 4; ++mi)
      af[mi] = ld_frag(&Qs[(mi * 16 + l16) * 72 + kb * 32 + quad * 8]);
#pragma unroll
    for (int mj = 0; mj < 4; ++mj)
      bfv[mj] = ld_frag(&Ks[(jw + mj * 16 + l16) * 72 + kb * 32 + quad * 8]);
#pragma unroll
    for (int mi = 0; mi < 4; ++mi)
#pragma unroll
      for (int mj = 0; mj < 4; ++mj)
        acc[mi][mj] = __builtin_amdgcn_mfma_f32_16x16x32_bf16(af[mi], bfv[mj], acc[mi][mj], 0, 0, 0);
  }

  // ---- softmax over 256 ----
  float rmax[4][4];
#pragma unroll
  for (int mi = 0; mi < 4; ++mi)
#pragma unroll
    for (int rr = 0; rr < 4; ++rr) {
      float m = fmaxf(fmaxf(acc[mi][0][rr], acc[mi][1][rr]),
                      fmaxf(acc[mi][2][rr], acc[mi][3][rr]));
      m = fmaxf(m, __shfl_xor(m, 1));
      m = fmaxf(m, __shfl_xor(m, 2));
      m = fmaxf(m, __shfl_xor(m, 4));
      m = fmaxf(m, __shfl_xor(m, 8));
      rmax[mi][rr] = m;
    }
  if (l16 == 0) {
#pragma unroll
    for (int mi = 0; mi < 4; ++mi)
#pragma unroll
      for (int rr = 0; rr < 4; ++rr)
        redm[wave][mi * 16 + quad * 4 + rr] = rmax[mi][rr];
  }
  __syncthreads();
  float gmax[4][4];
#pragma unroll
  for (int mi = 0; mi < 4; ++mi)
#pragma unroll
    for (int rr = 0; rr < 4; ++rr) {
      const int row = mi * 16 + quad * 4 + rr;
      gmax[mi][rr] = fmaxf(fmaxf(redm[0][row], redm[1][row]),
                           fmaxf(redm[2][row], redm[3][row]));
    }
  float rsum[4][4];
#pragma unroll
  for (int mi = 0; mi < 4; ++mi)
#pragma unroll
    for (int rr = 0; rr < 4; ++rr) {
      float s = 0.f;
#pragma unroll
      for (int mj = 0; mj < 4; ++mj) {
        float p = exp2f((acc[mi][mj][rr] - gmax[mi][rr]) * 1.4426950408889634f);
        acc[mi][mj][rr] = p;
        s += p;
      }
      s += __shfl_xor(s, 1);
      s += __shfl_xor(s, 2);
      s += __shfl_xor(s, 4);
      s += __shfl_xor(s, 8);
      rsum[mi][rr] = s;
    }
  if (l16 == 0) {
#pragma unroll
    for (int mi = 0; mi < 4; ++mi)
#pragma unroll
      for (int rr = 0; rr < 4; ++rr)
        reds[wave][mi * 16 + quad * 4 + rr] = rsum[mi][rr];
  }
  __syncthreads();
#pragma unroll
  for (int mi = 0; mi < 4; ++mi)
#pragma unroll
    for (int rr = 0; rr < 4; ++rr) {
      const int row = mi * 16 + quad * 4 + rr;
      const float inv = 1.0f / (reds[0][row] + reds[1][row] + reds[2][row] + reds[3][row]);
#pragma unroll
      for (int mj = 0; mj < 4; ++mj)
        Ps[row * 264 + jw + mj * 16 + l16] = f2bf(acc[mi][mj][rr] * inv);
    }
  __syncthreads();

  // ---- O = P V : wave handles d-slice [wave*16, wave*16+16) ----
  const int d0 = wave * 16;
  f32x4 acc2[4];
#pragma unroll
  for (int mi = 0; mi < 4; ++mi) acc2[mi] = zero;
#pragma unroll
  for (int kb = 0; kb < 8; ++kb) {
    bf16x8 bfv = ld_frag(&Vt[(d0 + l16) * 264 + kb * 32 + quad * 8]);
#pragma unroll
    for (int mi = 0; mi < 4; ++mi) {
      bf16x8 af = ld_frag(&Ps[(mi * 16 + l16) * 264 + kb * 32 + quad * 8]);
      acc2[mi] = __builtin_amdgcn_mfma_f32_16x16x32_bf16(af, bfv, acc2[mi], 0, 0, 0);
    }
  }
#pragma unroll
  for (int mi = 0; mi < 4; ++mi)
#pragma unroll
    for (int rr = 0; rr < 4; ++rr) {
      const int i = mi * 16 + quad * 4 + rr;
      Ob[(size_t)(qrow0 + i) * 1024 + colh + d0 + l16] = f2bf(acc2[mi][rr]);
    }
}

// ---------------------------------------------------------------------------
// head rows 0..62 of each batch: pure residual copy
// ---------------------------------------------------------------------------
__global__ __launch_bounds__(256) void head_copy(const float* __restrict__ h,
                                                 float* __restrict__ out) {
  const int idx4 = blockIdx.x * 256 + threadIdx.x;   // 0 .. 64511
  const int b = idx4 / 16128;
  const int rem = idx4 - b * 16128;
  const size_t o = (size_t)b * 2048 * 1024 + (size_t)rem * 4;
  *(float4*)&out[o] = *(const float4*)&h[o];
}

// ---------------------------------------------------------------------------
extern "C" void kernel_launch(void* const* d_in, const int* in_sizes, int n_in,
                              void* d_out, int out_size, void* d_ws, size_t ws_size,
                              hipStream_t stream) {
  const float* h     = (const float*)d_in[0];
  const float* e     = (const float*)d_in[1];
  const float* Wq    = (const float*)d_in[2];
  const float* bq    = (const float*)d_in[3];
  const float* Wk    = (const float*)d_in[4];
  const float* bk    = (const float*)d_in[5];
  const float* Wv    = (const float*)d_in[6];
  const float* bv    = (const float*)d_in[7];
  const float* Wo    = (const float*)d_in[8];
  const float* bo    = (const float*)d_in[9];
  const float* gamma = (const float*)d_in[10];
  const float* beta  = (const float*)d_in[11];
  float* out = (float*)d_out;

  // Workspace layout (exactly 184 MiB, proven safe):
  //   stg32: 32 MiB multi-use — LN out (hhb, first 16 MiB) -> e-cast halves
  //          (32 MiB) -> attention output Ob (first 16 MiB).
  char* ws = (char*)d_ws;
  ushort* stg  = (ushort*)(ws + ((size_t)0 << 20));    // 32 MiB
  ushort* WqT  = (ushort*)(ws + ((size_t)32 << 20));   // 2 MiB
  ushort* WkvT = (ushort*)(ws + ((size_t)34 << 20));   // 4 MiB (Wk | Wv)
  ushort* WoT  = (ushort*)(ws + ((size_t)38 << 20));   // 2 MiB
  ushort* Qb   = (ushort*)(ws + ((size_t)40 << 20));   // 16 MiB
  ushort* Kb   = (ushort*)(ws + ((size_t)56 << 20));   // 64 MiB
  ushort* VtG  = (ushort*)(ws + ((size_t)120 << 20));  // 64 MiB ([bch][64][256])

  // 1. weights -> bf16 transposed (one dispatch)
  transpose_cast4<<<dim3(16, 16, 4), 256, 0, stream>>>(Wq, Wk, Wv, Wo, WqT, WkvT, WoT);

  // 2. LayerNorm -> stg[0:16M] (bf16, padded)
  ln_kernel<<<8192, 256, 0, stream>>>(h, gamma, beta, stg);

  // 3. Q projection (scale 1/8 folded in; consumes LN output)
  gemm_bf16<0, 8><<<512, 256, 0, stream>>>(stg, WqT, bq, nullptr, Qb, nullptr,
                                           nullptr, nullptr, 64, 0.125f, 0);

  // 4. fused K|V projection in 2 halves of 16384 rows (e cast through stg).
  for (int half = 0; half < 2; ++half) {
    const size_t roff = (size_t)half * 16384 * 1024;
    cast_bf16<<<8192, 256, 0, stream>>>(e + roff, stg);
    gemm_bf16<2, 16><<<2048, 256, 0, stream>>>(stg, WkvT, bk, bv, Kb + roff,
                                               VtG, nullptr, nullptr,
                                               128, 1.0f, half * 16384);
  }

  // 5. attention per (b, chunk, head) -> Ob (= stg, dead region)
  attn_kernel<<<2048, 256, 0, stream>>>(Qb, Kb, VtG, stg);

  // 6. output projection + shifted residual (f32 out), plus first-63-row copy
  gemm_bf16<1, 8><<<512, 256, 0, stream>>>(stg, WoT, bo, nullptr, nullptr, nullptr,
                                           out, h, 64, 1.0f, 0);
  head_copy<<<252, 256, 0, stream>>>(h, out);
}